// Round 3
// baseline (2116.810 us; speedup 1.0000x reference)
//
#include <hip/hip_runtime.h>
#include <math.h>

// ---------------- constants ----------------
#define NBT   256    // B*T
#define NP    256    // points per frame
#define NC    10     // point channels
#define KNN   16
#define NPB   8      // points per block in edgeconv

__device__ __forceinline__ float gelu_f(float x) {
  return 0.5f * x * (1.0f + erff(x * 0.7071067811865476f));
}

// ---------------- K1: knn ----------------
// grid: NBT blocks, NP threads. idx[bt][p][k] = local neighbor index
__global__ __launch_bounds__(256) void knn_kernel(const float* __restrict__ x_pt,
                                                  int* __restrict__ idx) {
  __shared__ float sx[NP], sy[NP], sz[NP], ssq[NP];
  int bt = blockIdx.x, p = threadIdx.x;
  const float* xb = x_pt + (size_t)bt * NP * NC;
  float x0 = xb[p*NC+0], x1 = xb[p*NC+1], x2 = xb[p*NC+2];
  sx[p] = x0; sy[p] = x1; sz[p] = x2;
  float sq = x0*x0 + x1*x1 + x2*x2;
  ssq[p] = sq;
  __syncthreads();
  float bd[KNN]; int bi[KNN];
#pragma unroll
  for (int j = 0; j < KNN; ++j) { bd[j] = INFINITY; bi[j] = -1; }
  for (int q = 0; q < NP; ++q) {
    float dot = x0*sx[q] + x1*sy[q] + x2*sz[q];
    float d = sq + ssq[q] - 2.0f*dot;
    if (d < bd[KNN-1]) {   // strict: equal keeps earlier (smaller) index
      bd[KNN-1] = d; bi[KNN-1] = q;
#pragma unroll
      for (int j = KNN-1; j > 0; --j) {
        bool sw = bd[j] < bd[j-1];
        float td = sw ? bd[j-1] : bd[j];
        float tn = sw ? bd[j]   : bd[j-1];
        int   ti = sw ? bi[j-1] : bi[j];
        int   tm = sw ? bi[j]   : bi[j-1];
        bd[j] = td; bd[j-1] = tn; bi[j] = ti; bi[j-1] = tm;
      }
    }
  }
  int* ob = idx + ((size_t)bt*NP + p)*KNN;
#pragma unroll
  for (int j = 0; j < KNN; ++j) ob[j] = bi[j];
}

// ---------------- K2: factored layer-1 features ----------------
// A[p][o] = sum_e x[p][e]*(W1[o][e]-W2[o][e]);  B[p][o] = sum_e x[p][e]*W2[o][e]
__global__ __launch_bounds__(256) void featAB_kernel(const float* __restrict__ x_pt,
                                                     const float* __restrict__ ew1,
                                                     float* __restrict__ Af,
                                                     float* __restrict__ Bf) {
  int t = blockIdx.x*256 + threadIdx.x;
  int o = t & 63, p = t >> 6;
  const float* xr = x_pt + (size_t)p*NC;
  float a = 0.f, b = 0.f;
#pragma unroll
  for (int e = 0; e < NC; ++e) {
    float w1 = ew1[o*20 + e], w2 = ew1[o*20 + 10 + e];
    float xv = xr[e];
    a = fmaf(xv, w1 - w2, a);
    b = fmaf(xv, w2, b);
  }
  Af[(size_t)p*64 + o] = a;
  Bf[(size_t)p*64 + o] = b;
}

// ---------------- K3: edgeconv layer2 + max over k ----------------
// grid: 65536/NPB blocks, 256 threads. local[p][q] (q<128)
__global__ __launch_bounds__(256) void edgeconv_kernel(
    const float* __restrict__ Af, const float* __restrict__ Bf,
    const int* __restrict__ idx, const float* __restrict__ ew2,
    const float* __restrict__ eg1, const float* __restrict__ eb1,
    const float* __restrict__ em1, const float* __restrict__ ev1,
    const float* __restrict__ eg2, const float* __restrict__ eb2,
    const float* __restrict__ em2, const float* __restrict__ ev2,
    float* __restrict__ localf) {
  __shared__ __align__(16) float w2s[64*128];       // ew2T[o][q]
  __shared__ __align__(16) float h1s[NPB*64*20];    // [pt][o][k] row stride 20
  __shared__ float sc1[64], sh1[64], sc2[128], sh2[128];
  __shared__ int idxs[NPB*16];

  int tid = threadIdx.x;
  int p0  = blockIdx.x * NPB;         // global point id base
  int bt  = p0 >> 8;

  for (int i = tid; i < 8192; i += 256) {
    int q = i >> 6, o = i & 63;
    w2s[o*128 + q] = ew2[i];
  }
  // FIX(r2): was tid in [192,320) with 256 threads -> idxs[64..127] garbage
  if (tid < 128) {
    idxs[tid] = idx[(size_t)p0*16 + tid];
  }
  if (tid < 64) {
    float s = eg1[tid] * (1.0f / sqrtf(ev1[tid] + 1e-5f));
    sc1[tid] = s; sh1[tid] = eb1[tid] - em1[tid]*s;
  }
  if (tid >= 64 && tid < 192) {
    int q = tid - 64;
    float s = eg2[q] * (1.0f / sqrtf(ev2[q] + 1e-5f));
    sc2[q] = s; sh2[q] = eb2[q] - em2[q]*s;
  }
  __syncthreads();

  // build h1 = gelu(bn1(A[p] + B[idx])) into h1s[pt][o][k]
  // thread (o = tid&63, g = tid>>6) handles points {2g, 2g+1}, all k
  {
    int o = tid & 63, g = tid >> 6;
    float s1 = sc1[o], h1 = sh1[o];
    const float* Bbase = Bf + (size_t)bt*NP*64 + o;
#pragma unroll
    for (int pi = 0; pi < 2; ++pi) {
      int pt = g*2 + pi;
      float af = Af[((size_t)(p0+pt))*64 + o];
      float* hrow = h1s + pt*1280 + o*20;
      for (int k = 0; k < KNN; ++k) {
        int j = idxs[pt*16 + k];
        float hv = af + Bbase[(size_t)j*64];
        hrow[k] = gelu_f(fmaf(hv, s1, h1));
      }
    }
  }
  __syncthreads();

  // 32 threads per point, 8k x 8q register tile
  int pt = tid >> 5, s = tid & 31;
  int kb = s & 1, qb = s >> 1;
  int k0 = kb*8, q0 = qb*8;
  float acc[8][8];
#pragma unroll
  for (int a = 0; a < 8; ++a)
#pragma unroll
    for (int b = 0; b < 8; ++b) acc[a][b] = 0.f;

  const float* hbase = h1s + pt*1280;
#pragma unroll 2
  for (int o = 0; o < 64; ++o) {
    float4 a0 = *(const float4*)(hbase + o*20 + k0);
    float4 a1 = *(const float4*)(hbase + o*20 + k0 + 4);
    float4 b0 = *(const float4*)(w2s + o*128 + q0);
    float4 b1 = *(const float4*)(w2s + o*128 + q0 + 4);
    float av[8] = {a0.x,a0.y,a0.z,a0.w,a1.x,a1.y,a1.z,a1.w};
    float bv[8] = {b0.x,b0.y,b0.z,b0.w,b1.x,b1.y,b1.z,b1.w};
#pragma unroll
    for (int ki = 0; ki < 8; ++ki)
#pragma unroll
      for (int qi = 0; qi < 8; ++qi)
        acc[ki][qi] = fmaf(av[ki], bv[qi], acc[ki][qi]);
  }

  // bn2 affine, then min/max over k. gelu is quasiconvex (valley at ~-0.7518):
  // max_k gelu(y_k) == max(gelu(min_k y), gelu(max_k y)).  2 gelu per (pt,q),
  // qi split across the kb lane-pair -> 8 erff per thread (was 64).
  float mn8[8], mx8[8];
#pragma unroll
  for (int qi = 0; qi < 8; ++qi) {
    float sc = sc2[q0+qi], sh = sh2[q0+qi];
    float mn = INFINITY, mx = -INFINITY;
#pragma unroll
    for (int ki = 0; ki < 8; ++ki) {
      float v = fmaf(acc[ki][qi], sc, sh);
      mn = fminf(mn, v); mx = fmaxf(mx, v);
    }
    mn = fminf(mn, __shfl_xor(mn, 1));
    mx = fmaxf(mx, __shfl_xor(mx, 1));
    mn8[qi] = mn; mx8[qi] = mx;
  }
  float g4[4];
#pragma unroll
  for (int j = 0; j < 4; ++j) {
    int qi = kb*4 + j;
    g4[j] = fmaxf(gelu_f(mn8[qi]), gelu_f(mx8[qi]));
  }
  float o4[4];
#pragma unroll
  for (int j = 0; j < 4; ++j) o4[j] = __shfl_xor(g4[j], 1);
  if (kb == 0) {
    float* op = localf + ((size_t)(p0+pt))*128 + q0;
    *(float4*)op     = make_float4(g4[0],g4[1],g4[2],g4[3]);
    *(float4*)(op+4) = make_float4(o4[0],o4[1],o4[2],o4[3]);
  }
}

// ---------------- K4: p1 -> LN -> gelu -> p2 -> LN -> gelu -> max/mean pool (+frame MLP) ----------------
// grid: NBT blocks, 512 threads. 32 points per chunk, 8 chunks.
__global__ __launch_bounds__(512) void p1p2_kernel(
    const float* __restrict__ localf, const float* __restrict__ x_pt,
    const float* __restrict__ p1w, const float* __restrict__ p1b,
    const float* __restrict__ ln1g, const float* __restrict__ ln1b,
    const float* __restrict__ p2w, const float* __restrict__ p2b,
    const float* __restrict__ ln2g, const float* __restrict__ ln2b,
    const float* __restrict__ xfr, const float* __restrict__ f1w,
    const float* __restrict__ f1b, const float* __restrict__ f2w,
    const float* __restrict__ f2b,
    float* __restrict__ perbuf) {
  __shared__ float feat[32*138];
  __shared__ float h1c[32*132];
  __shared__ float poolm[32*256];
  __shared__ float pools[32*256];
  int bt = blockIdx.x, tid = threadIdx.x;
  int pt = tid >> 4, sg = tid & 15;

  float pmax[16], psum[16];
#pragma unroll
  for (int j = 0; j < 16; ++j) { pmax[j] = -INFINITY; psum[j] = 0.f; }

  for (int ch = 0; ch < 8; ++ch) {
    __syncthreads();
    for (int i = tid; i < 32*138; i += 512) {
      int pp = i / 138, e = i - pp*138;
      size_t gp = (size_t)bt*NP + ch*32 + pp;
      feat[i] = (e < 128) ? localf[gp*128 + e] : x_pt[gp*NC + (e - 128)];
    }
    __syncthreads();

    // GEMM1: 8 outputs o = sg*8 + j
    float a[8];
#pragma unroll
    for (int j = 0; j < 8; ++j) a[j] = p1b[sg*8 + j];
    const float* fr = feat + pt*138;
    for (int e = 0; e < 138; ++e) {
      float fv = fr[e];
      float4 w0 = *(const float4*)(p1w + e*128 + sg*8);
      float4 w1 = *(const float4*)(p1w + e*128 + sg*8 + 4);
      a[0]=fmaf(fv,w0.x,a[0]); a[1]=fmaf(fv,w0.y,a[1]);
      a[2]=fmaf(fv,w0.z,a[2]); a[3]=fmaf(fv,w0.w,a[3]);
      a[4]=fmaf(fv,w1.x,a[4]); a[5]=fmaf(fv,w1.y,a[5]);
      a[6]=fmaf(fv,w1.z,a[6]); a[7]=fmaf(fv,w1.w,a[7]);
    }
    // LN over 128 (16 lanes x 8)
    float s = 0.f;
#pragma unroll
    for (int j = 0; j < 8; ++j) s += a[j];
    s += __shfl_xor(s,1); s += __shfl_xor(s,2); s += __shfl_xor(s,4); s += __shfl_xor(s,8);
    float mu = s * (1.0f/128.0f);
    float s2 = 0.f;
#pragma unroll
    for (int j = 0; j < 8; ++j) { float ddf = a[j]-mu; s2 += ddf*ddf; }
    s2 += __shfl_xor(s2,1); s2 += __shfl_xor(s2,2); s2 += __shfl_xor(s2,4); s2 += __shfl_xor(s2,8);
    float rs = 1.0f / sqrtf(s2*(1.0f/128.0f) + 1e-5f);
#pragma unroll
    for (int j = 0; j < 8; ++j) {
      float y = (a[j]-mu)*rs*ln1g[sg*8+j] + ln1b[sg*8+j];
      h1c[pt*132 + sg*8 + j] = gelu_f(y);
    }
    __syncthreads();

    // GEMM2: 16 outputs q = sg*16 + j
    float c2[16];
#pragma unroll
    for (int j = 0; j < 16; ++j) c2[j] = p2b[sg*16 + j];
    const float* hr = h1c + pt*132;
    for (int e = 0; e < 128; ++e) {
      float hv = hr[e];
      float4 w0 = *(const float4*)(p2w + e*256 + sg*16);
      float4 w1 = *(const float4*)(p2w + e*256 + sg*16 + 4);
      float4 w2v = *(const float4*)(p2w + e*256 + sg*16 + 8);
      float4 w3 = *(const float4*)(p2w + e*256 + sg*16 + 12);
      c2[0]=fmaf(hv,w0.x,c2[0]);  c2[1]=fmaf(hv,w0.y,c2[1]);
      c2[2]=fmaf(hv,w0.z,c2[2]);  c2[3]=fmaf(hv,w0.w,c2[3]);
      c2[4]=fmaf(hv,w1.x,c2[4]);  c2[5]=fmaf(hv,w1.y,c2[5]);
      c2[6]=fmaf(hv,w1.z,c2[6]);  c2[7]=fmaf(hv,w1.w,c2[7]);
      c2[8]=fmaf(hv,w2v.x,c2[8]); c2[9]=fmaf(hv,w2v.y,c2[9]);
      c2[10]=fmaf(hv,w2v.z,c2[10]); c2[11]=fmaf(hv,w2v.w,c2[11]);
      c2[12]=fmaf(hv,w3.x,c2[12]); c2[13]=fmaf(hv,w3.y,c2[13]);
      c2[14]=fmaf(hv,w3.z,c2[14]); c2[15]=fmaf(hv,w3.w,c2[15]);
    }
    // LN over 256 (16 lanes x 16)
    float t1 = 0.f;
#pragma unroll
    for (int j = 0; j < 16; ++j) t1 += c2[j];
    t1 += __shfl_xor(t1,1); t1 += __shfl_xor(t1,2); t1 += __shfl_xor(t1,4); t1 += __shfl_xor(t1,8);
    float mu2 = t1 * (1.0f/256.0f);
    float t2 = 0.f;
#pragma unroll
    for (int j = 0; j < 16; ++j) { float dd = c2[j]-mu2; t2 += dd*dd; }
    t2 += __shfl_xor(t2,1); t2 += __shfl_xor(t2,2); t2 += __shfl_xor(t2,4); t2 += __shfl_xor(t2,8);
    float rs2 = 1.0f / sqrtf(t2*(1.0f/256.0f) + 1e-5f);
#pragma unroll
    for (int j = 0; j < 16; ++j) {
      float y = (c2[j]-mu2)*rs2*ln2g[sg*16+j] + ln2b[sg*16+j];
      float v = gelu_f(y);
      pmax[j] = fmaxf(pmax[j], v);
      psum[j] += v;
    }
  }

  __syncthreads();
#pragma unroll
  for (int j = 0; j < 16; ++j) {
    poolm[pt*256 + sg*16 + j] = pmax[j];
    pools[pt*256 + sg*16 + j] = psum[j];
  }
  __syncthreads();
  int q = tid & 255;
  if (tid < 256) {
    float mx = -INFINITY;
    for (int sl = 0; sl < 32; ++sl) mx = fmaxf(mx, poolm[sl*256 + q]);
    perbuf[(size_t)bt*576 + q] = mx;
  } else {
    float sm = 0.f;
    for (int sl = 0; sl < 32; ++sl) sm += pools[sl*256 + q];
    perbuf[(size_t)bt*576 + 256 + q] = sm * (1.0f/256.0f);
  }

  // fused frame MLP: 64 outputs for row bt (redundant h across 64 lanes, trivial)
  if (tid < 64) {
    float x0 = xfr[bt*4], x1 = xfr[bt*4+1], x2 = xfr[bt*4+2], x3 = xfr[bt*4+3];
    float acc = f2b[tid];
#pragma unroll
    for (int e = 0; e < 32; ++e) {
      float hv = f1b[e];
      hv = fmaf(x0, f1w[e], hv);
      hv = fmaf(x1, f1w[32+e], hv);
      hv = fmaf(x2, f1w[64+e], hv);
      hv = fmaf(x3, f1w[96+e], hv);
      acc = fmaf(gelu_f(hv), f2w[e*64 + tid], acc);
    }
    perbuf[(size_t)bt*576 + 512 + tid] = acc;
  }
}

// ---------------- K6: 1x1 projection conv ----------------
__global__ __launch_bounds__(256) void proj_kernel(
    const float* __restrict__ per, const float* __restrict__ projw,
    const float* __restrict__ projb, float* __restrict__ hout) {
  __shared__ __align__(16) float sp[576];
  int bt = blockIdx.x, c = threadIdx.x;
  for (int i = c; i < 576; i += 256) sp[i] = per[(size_t)bt*576 + i];
  __syncthreads();
  float acc = projb[c];
  const float* wr = projw + (size_t)c*576;
  for (int i = 0; i < 144; ++i) {
    float4 wv = *(const float4*)(wr + i*4);
    float4 pv = *(const float4*)(sp + i*4);
    acc = fmaf(wv.x, pv.x, acc); acc = fmaf(wv.y, pv.y, acc);
    acc = fmaf(wv.z, pv.z, acc); acc = fmaf(wv.w, pv.w, acc);
  }
  hout[(size_t)bt*256 + c] = acc;
}

// ---------------- K7: conv3 + bn + gelu (+residual) ----------------
__global__ __launch_bounds__(256) void conv_bn_kernel(
    const float* __restrict__ hin, float* __restrict__ hout,
    const float* __restrict__ w, const float* __restrict__ bias,
    const float* __restrict__ g, const float* __restrict__ be,
    const float* __restrict__ m, const float* __restrict__ v,
    int residual) {
  __shared__ __align__(16) float win[768];   // [cin][dt]
  int bt = blockIdx.x, b = bt >> 5, t = bt & 31;
  int c = threadIdx.x;
  for (int i = c; i < 768; i += 256) {
    int cin = i / 3, dt = i - cin*3;
    int tt = t + dt - 1;
    win[i] = (tt >= 0 && tt < 32) ? hin[((size_t)b*32 + tt)*256 + cin] : 0.0f;
  }
  __syncthreads();
  float acc = bias[c];
  const float* wr = w + (size_t)c*768;
  for (int i = 0; i < 192; ++i) {
    float4 wv = *(const float4*)(wr + i*4);
    float4 pv = *(const float4*)(win + i*4);
    acc = fmaf(wv.x, pv.x, acc); acc = fmaf(wv.y, pv.y, acc);
    acc = fmaf(wv.z, pv.z, acc); acc = fmaf(wv.w, pv.w, acc);
  }
  float rsv = 1.0f / sqrtf(v[c] + 1e-5f);
  float y = (acc - m[c]) * rsv * g[c] + be[c];
  y = gelu_f(y);
  if (residual) y += win[c*3 + 1];
  hout[(size_t)bt*256 + c] = y;
}

// ---------------- K8: max-pool over T + head ----------------
__global__ __launch_bounds__(256) void poolhead_kernel(
    const float* __restrict__ hs, const float* __restrict__ h1w,
    const float* __restrict__ h1b, const float* __restrict__ h2w,
    const float* __restrict__ h2b, float* __restrict__ out) {
  __shared__ float pooled[256];
  __shared__ float hh[128];
  int b = blockIdx.x, tid = threadIdx.x;
  float mx = -INFINITY;
  for (int t = 0; t < 32; ++t)
    mx = fmaxf(mx, hs[((size_t)b*32 + t)*256 + tid]);
  pooled[tid] = mx;
  __syncthreads();
  if (tid < 128) {
    float acc = h1b[tid];
    for (int e = 0; e < 256; ++e) acc = fmaf(pooled[e], h1w[e*128 + tid], acc);
    hh[tid] = gelu_f(acc);
  }
  __syncthreads();
  if (tid < 25) {
    float acc = h2b[tid];
    for (int e = 0; e < 128; ++e) acc = fmaf(hh[e], h2w[e*25 + tid], acc);
    out[b*25 + tid] = acc;
  }
}

// ---------------- launch ----------------
extern "C" void kernel_launch(void* const* d_in, const int* in_sizes, int n_in,
                              void* d_out, int out_size, void* d_ws, size_t ws_size,
                              hipStream_t stream) {
  const float* x_pt = (const float*)d_in[0];
  const float* x_fr = (const float*)d_in[1];
  const float* ew1  = (const float*)d_in[2];
  const float* eg1  = (const float*)d_in[3];
  const float* eb1  = (const float*)d_in[4];
  const float* em1  = (const float*)d_in[5];
  const float* ev1  = (const float*)d_in[6];
  const float* ew2  = (const float*)d_in[7];
  const float* eg2  = (const float*)d_in[8];
  const float* eb2  = (const float*)d_in[9];
  const float* em2  = (const float*)d_in[10];
  const float* ev2  = (const float*)d_in[11];
  const float* p1w  = (const float*)d_in[12];
  const float* p1b  = (const float*)d_in[13];
  const float* ln1g = (const float*)d_in[14];
  const float* ln1b = (const float*)d_in[15];
  const float* p2w  = (const float*)d_in[16];
  const float* p2b  = (const float*)d_in[17];
  const float* ln2g = (const float*)d_in[18];
  const float* ln2b = (const float*)d_in[19];
  const float* f1w  = (const float*)d_in[20];
  const float* f1b  = (const float*)d_in[21];
  const float* f2w  = (const float*)d_in[22];
  const float* f2b  = (const float*)d_in[23];
  const float* projw= (const float*)d_in[24];
  const float* projb= (const float*)d_in[25];
  const float* cw[4] = {(const float*)d_in[26],(const float*)d_in[32],(const float*)d_in[38],(const float*)d_in[44]};
  const float* cb[4] = {(const float*)d_in[27],(const float*)d_in[33],(const float*)d_in[39],(const float*)d_in[45]};
  const float* cg[4] = {(const float*)d_in[28],(const float*)d_in[34],(const float*)d_in[40],(const float*)d_in[46]};
  const float* cbe[4]= {(const float*)d_in[29],(const float*)d_in[35],(const float*)d_in[41],(const float*)d_in[47]};
  const float* cm[4] = {(const float*)d_in[30],(const float*)d_in[36],(const float*)d_in[42],(const float*)d_in[48]};
  const float* cv[4] = {(const float*)d_in[31],(const float*)d_in[37],(const float*)d_in[43],(const float*)d_in[49]};
  const float* h1w  = (const float*)d_in[50];
  const float* h1b  = (const float*)d_in[51];
  const float* h2w  = (const float*)d_in[52];
  const float* h2b  = (const float*)d_in[53];
  float* out = (float*)d_out;

  char* ws = (char*)d_ws;
  // region0 (0..4MB): idx during KNN/edgeconv; reused afterwards for per/hs
  int*   idxw   = (int*)ws;                                   // 4 MB (1,048,576 int)
  float* perbuf = (float*)ws;                                 // 589,824 B (after edgeconv done)
  float* hs0    = (float*)(ws + 0x90000);                     // 262,144 B each
  float* hs1    = (float*)(ws + 0x90000 + 0x40000);
  float* hs2    = (float*)(ws + 0x90000 + 2*0x40000);
  float* hs3    = (float*)(ws + 0x90000 + 3*0x40000);
  float* hs4    = (float*)(ws + 0x90000 + 4*0x40000);
  float* Af     = (float*)(ws + ((size_t)4  << 20));          // 16 MB
  float* Bfw    = (float*)(ws + ((size_t)20 << 20));          // 16 MB
  float* localf = (float*)(ws + ((size_t)36 << 20));          // 32 MB

  knn_kernel<<<NBT, 256, 0, stream>>>(x_pt, idxw);
  featAB_kernel<<<(NBT*NP*64)/256, 256, 0, stream>>>(x_pt, ew1, Af, Bfw);
  edgeconv_kernel<<<(NBT*NP)/NPB, 256, 0, stream>>>(Af, Bfw, idxw, ew2,
      eg1, eb1, em1, ev1, eg2, eb2, em2, ev2, localf);
  p1p2_kernel<<<NBT, 512, 0, stream>>>(localf, x_pt, p1w, p1b, ln1g, ln1b,
      p2w, p2b, ln2g, ln2b, x_fr, f1w, f1b, f2w, f2b, perbuf);
  proj_kernel<<<NBT, 256, 0, stream>>>(perbuf, projw, projb, hs0);
  conv_bn_kernel<<<NBT, 256, 0, stream>>>(hs0, hs1, cw[0], cb[0], cg[0], cbe[0], cm[0], cv[0], 0);
  conv_bn_kernel<<<NBT, 256, 0, stream>>>(hs1, hs2, cw[1], cb[1], cg[1], cbe[1], cm[1], cv[1], 1);
  conv_bn_kernel<<<NBT, 256, 0, stream>>>(hs2, hs3, cw[2], cb[2], cg[2], cbe[2], cm[2], cv[2], 1);
  conv_bn_kernel<<<NBT, 256, 0, stream>>>(hs3, hs4, cw[3], cb[3], cg[3], cbe[3], cm[3], cv[3], 1);
  poolhead_kernel<<<8, 256, 0, stream>>>(hs4, h1w, h1b, h2w, h2b, out);
}

// Round 4
// 1422.710 us; speedup vs baseline: 1.4879x; 1.4879x over previous
//
#include <hip/hip_runtime.h>
#include <math.h>

// ---------------- constants ----------------
#define NBT   256    // B*T
#define NP    256    // points per frame
#define NC    10     // point channels
#define KNN   16
#define NPB   8      // points per block in edgeconv

__device__ __forceinline__ float gelu_f(float x) {
  return 0.5f * x * (1.0f + erff(x * 0.7071067811865476f));
}

// ---------------- K1: knn (wave-per-point, branchless top-16) ----------------
// grid: NBT*64 blocks, 256 threads (4 waves = 4 points per block).
// Key pack: (float_bits(max(d,0)) & ~0xFF) | q  -> uint-min == (dist, idx) lexicographic min.
__global__ __launch_bounds__(256) void knn_kernel(const float* __restrict__ x_pt,
                                                  int* __restrict__ idx) {
  __shared__ float sx[NP], sy[NP], sz[NP], ssq[NP];
  int bt = blockIdx.x >> 6;             // 64 blocks per frame
  int p0 = (blockIdx.x & 63) * 4;       // 4 points per block
  int tid = threadIdx.x;
  const float* xb = x_pt + (size_t)bt * NP * NC;
  {
    int q = tid;
    float x0 = xb[q*NC+0], x1 = xb[q*NC+1], x2 = xb[q*NC+2];
    sx[q] = x0; sy[q] = x1; sz[q] = x2;
    ssq[q] = x0*x0 + x1*x1 + x2*x2;
  }
  __syncthreads();

  int wv = tid >> 6, lane = tid & 63;
  int p = p0 + wv;
  float px = sx[p], py = sy[p], pz = sz[p], psq = ssq[p];

  unsigned k0, k1, k2, k3;
  {
    unsigned kk[4];
#pragma unroll
    for (int c = 0; c < 4; ++c) {
      int q = lane + c*64;
      float d = psq + ssq[q] - 2.0f*(px*sx[q] + py*sy[q] + pz*sz[q]);
      d = fmaxf(d, 0.0f);
      kk[c] = (__float_as_uint(d) & 0xFFFFFF00u) | (unsigned)q;
    }
    // sort 4 (network: (0,1)(2,3)(0,2)(1,3)(1,2))
    unsigned a0 = min(kk[0], kk[1]), a1 = max(kk[0], kk[1]);
    unsigned a2 = min(kk[2], kk[3]), a3 = max(kk[2], kk[3]);
    unsigned b0 = min(a0, a2), b2 = max(a0, a2);
    unsigned b1 = min(a1, a3), b3 = max(a1, a3);
    k0 = b0; k1 = min(b1, b2); k2 = max(b1, b2); k3 = b3;
  }

  // 16 extraction rounds: butterfly uint-min over lane heads; winner pops.
  unsigned cur = k0, mykeep = 0u;
#pragma unroll
  for (int r = 0; r < 16; ++r) {
    unsigned w = cur;
    w = min(w, (unsigned)__shfl_xor((int)w, 1));
    w = min(w, (unsigned)__shfl_xor((int)w, 2));
    w = min(w, (unsigned)__shfl_xor((int)w, 4));
    w = min(w, (unsigned)__shfl_xor((int)w, 8));
    w = min(w, (unsigned)__shfl_xor((int)w, 16));
    w = min(w, (unsigned)__shfl_xor((int)w, 32));
    bool win = (cur == w);                 // keys unique -> exactly one winner
    cur = win ? k1 : cur;
    k1  = win ? k2 : k1;
    k2  = win ? k3 : k2;
    k3  = win ? 0xFFFFFFFFu : k3;
    if (lane == r) mykeep = w;
  }
  if (lane < 16)
    idx[((size_t)bt*NP + p)*KNN + lane] = (int)(mykeep & 0xFFu);
}

// ---------------- K2: factored layer-1 features ----------------
// A[p][o] = sum_e x[p][e]*(W1[o][e]-W2[o][e]);  B[p][o] = sum_e x[p][e]*W2[o][e]
__global__ __launch_bounds__(256) void featAB_kernel(const float* __restrict__ x_pt,
                                                     const float* __restrict__ ew1,
                                                     float* __restrict__ Af,
                                                     float* __restrict__ Bf) {
  int t = blockIdx.x*256 + threadIdx.x;
  int o = t & 63, p = t >> 6;
  const float* xr = x_pt + (size_t)p*NC;
  float a = 0.f, b = 0.f;
#pragma unroll
  for (int e = 0; e < NC; ++e) {
    float w1 = ew1[o*20 + e], w2 = ew1[o*20 + 10 + e];
    float xv = xr[e];
    a = fmaf(xv, w1 - w2, a);
    b = fmaf(xv, w2, b);
  }
  Af[(size_t)p*64 + o] = a;
  Bf[(size_t)p*64 + o] = b;
}

// ---------------- K3: edgeconv layer2 + max over k ----------------
// grid: 65536/NPB blocks, 256 threads. local[p][q] (q<128)
__global__ __launch_bounds__(256) void edgeconv_kernel(
    const float* __restrict__ Af, const float* __restrict__ Bf,
    const int* __restrict__ idx, const float* __restrict__ ew2,
    const float* __restrict__ eg1, const float* __restrict__ eb1,
    const float* __restrict__ em1, const float* __restrict__ ev1,
    const float* __restrict__ eg2, const float* __restrict__ eb2,
    const float* __restrict__ em2, const float* __restrict__ ev2,
    float* __restrict__ localf) {
  __shared__ __align__(16) float w2s[64*128];       // ew2T[o][q]
  __shared__ __align__(16) float h1s[NPB*64*20];    // [pt][o][k] row stride 20
  __shared__ float sc1[64], sh1[64], sc2[128], sh2[128];
  __shared__ int idxs[NPB*16];

  int tid = threadIdx.x;
  int p0  = blockIdx.x * NPB;         // global point id base
  int bt  = p0 >> 8;

  for (int i = tid; i < 8192; i += 256) {
    int q = i >> 6, o = i & 63;
    w2s[o*128 + q] = ew2[i];
  }
  if (tid < 128) {
    idxs[tid] = idx[(size_t)p0*16 + tid];
  }
  if (tid < 64) {
    float s = eg1[tid] * (1.0f / sqrtf(ev1[tid] + 1e-5f));
    sc1[tid] = s; sh1[tid] = eb1[tid] - em1[tid]*s;
  }
  if (tid >= 64 && tid < 192) {
    int q = tid - 64;
    float s = eg2[q] * (1.0f / sqrtf(ev2[q] + 1e-5f));
    sc2[q] = s; sh2[q] = eb2[q] - em2[q]*s;
  }
  __syncthreads();

  // build h1 = gelu(bn1(A[p] + B[idx])) into h1s[pt][o][k]
  {
    int o = tid & 63, g = tid >> 6;
    float s1 = sc1[o], h1 = sh1[o];
    const float* Bbase = Bf + (size_t)bt*NP*64 + o;
#pragma unroll
    for (int pi = 0; pi < 2; ++pi) {
      int pt = g*2 + pi;
      float af = Af[((size_t)(p0+pt))*64 + o];
      float* hrow = h1s + pt*1280 + o*20;
      for (int k = 0; k < KNN; ++k) {
        int j = idxs[pt*16 + k];
        float hv = af + Bbase[(size_t)j*64];
        hrow[k] = gelu_f(fmaf(hv, s1, h1));
      }
    }
  }
  __syncthreads();

  // 32 threads per point, 8k x 8q register tile
  int pt = tid >> 5, s = tid & 31;
  int kb = s & 1, qb = s >> 1;
  int k0 = kb*8, q0 = qb*8;
  float acc[8][8];
#pragma unroll
  for (int a = 0; a < 8; ++a)
#pragma unroll
    for (int b = 0; b < 8; ++b) acc[a][b] = 0.f;

  const float* hbase = h1s + pt*1280;
#pragma unroll 2
  for (int o = 0; o < 64; ++o) {
    float4 a0 = *(const float4*)(hbase + o*20 + k0);
    float4 a1 = *(const float4*)(hbase + o*20 + k0 + 4);
    float4 b0 = *(const float4*)(w2s + o*128 + q0);
    float4 b1 = *(const float4*)(w2s + o*128 + q0 + 4);
    float av[8] = {a0.x,a0.y,a0.z,a0.w,a1.x,a1.y,a1.z,a1.w};
    float bv[8] = {b0.x,b0.y,b0.z,b0.w,b1.x,b1.y,b1.z,b1.w};
#pragma unroll
    for (int ki = 0; ki < 8; ++ki)
#pragma unroll
      for (int qi = 0; qi < 8; ++qi)
        acc[ki][qi] = fmaf(av[ki], bv[qi], acc[ki][qi]);
  }

  // bn2 affine, then min/max over k; gelu quasiconvex ->
  // max_k gelu(y_k) == max(gelu(min_k y), gelu(max_k y))
  float mn8[8], mx8[8];
#pragma unroll
  for (int qi = 0; qi < 8; ++qi) {
    float sc = sc2[q0+qi], sh = sh2[q0+qi];
    float mn = INFINITY, mx = -INFINITY;
#pragma unroll
    for (int ki = 0; ki < 8; ++ki) {
      float v = fmaf(acc[ki][qi], sc, sh);
      mn = fminf(mn, v); mx = fmaxf(mx, v);
    }
    mn = fminf(mn, __shfl_xor(mn, 1));
    mx = fmaxf(mx, __shfl_xor(mx, 1));
    mn8[qi] = mn; mx8[qi] = mx;
  }
  float g4[4];
#pragma unroll
  for (int j = 0; j < 4; ++j) {
    int qi = kb*4 + j;
    g4[j] = fmaxf(gelu_f(mn8[qi]), gelu_f(mx8[qi]));
  }
  float o4[4];
#pragma unroll
  for (int j = 0; j < 4; ++j) o4[j] = __shfl_xor(g4[j], 1);
  if (kb == 0) {
    float* op = localf + ((size_t)(p0+pt))*128 + q0;
    *(float4*)op     = make_float4(g4[0],g4[1],g4[2],g4[3]);
    *(float4*)(op+4) = make_float4(o4[0],o4[1],o4[2],o4[3]);
  }
}

// ---------------- K4: p1 -> LN -> gelu -> p2 -> LN -> gelu -> max/mean pool (+frame MLP) ----------------
// grid: NBT blocks, 512 threads. 32 points per chunk, 8 chunks.
__global__ __launch_bounds__(512) void p1p2_kernel(
    const float* __restrict__ localf, const float* __restrict__ x_pt,
    const float* __restrict__ p1w, const float* __restrict__ p1b,
    const float* __restrict__ ln1g, const float* __restrict__ ln1b,
    const float* __restrict__ p2w, const float* __restrict__ p2b,
    const float* __restrict__ ln2g, const float* __restrict__ ln2b,
    const float* __restrict__ xfr, const float* __restrict__ f1w,
    const float* __restrict__ f1b, const float* __restrict__ f2w,
    const float* __restrict__ f2b,
    float* __restrict__ perbuf) {
  __shared__ float feat[32*138];
  __shared__ float h1c[32*132];
  __shared__ float poolm[32*256];
  __shared__ float pools[32*256];
  int bt = blockIdx.x, tid = threadIdx.x;
  int pt = tid >> 4, sg = tid & 15;

  float pmax[16], psum[16];
#pragma unroll
  for (int j = 0; j < 16; ++j) { pmax[j] = -INFINITY; psum[j] = 0.f; }

  for (int ch = 0; ch < 8; ++ch) {
    __syncthreads();
    for (int i = tid; i < 32*138; i += 512) {
      int pp = i / 138, e = i - pp*138;
      size_t gp = (size_t)bt*NP + ch*32 + pp;
      feat[i] = (e < 128) ? localf[gp*128 + e] : x_pt[gp*NC + (e - 128)];
    }
    __syncthreads();

    // GEMM1: 8 outputs o = sg*8 + j
    float a[8];
#pragma unroll
    for (int j = 0; j < 8; ++j) a[j] = p1b[sg*8 + j];
    const float* fr = feat + pt*138;
    for (int e = 0; e < 138; ++e) {
      float fv = fr[e];
      float4 w0 = *(const float4*)(p1w + e*128 + sg*8);
      float4 w1 = *(const float4*)(p1w + e*128 + sg*8 + 4);
      a[0]=fmaf(fv,w0.x,a[0]); a[1]=fmaf(fv,w0.y,a[1]);
      a[2]=fmaf(fv,w0.z,a[2]); a[3]=fmaf(fv,w0.w,a[3]);
      a[4]=fmaf(fv,w1.x,a[4]); a[5]=fmaf(fv,w1.y,a[5]);
      a[6]=fmaf(fv,w1.z,a[6]); a[7]=fmaf(fv,w1.w,a[7]);
    }
    // LN over 128 (16 lanes x 8)
    float s = 0.f;
#pragma unroll
    for (int j = 0; j < 8; ++j) s += a[j];
    s += __shfl_xor(s,1); s += __shfl_xor(s,2); s += __shfl_xor(s,4); s += __shfl_xor(s,8);
    float mu = s * (1.0f/128.0f);
    float s2 = 0.f;
#pragma unroll
    for (int j = 0; j < 8; ++j) { float ddf = a[j]-mu; s2 += ddf*ddf; }
    s2 += __shfl_xor(s2,1); s2 += __shfl_xor(s2,2); s2 += __shfl_xor(s2,4); s2 += __shfl_xor(s2,8);
    float rs = 1.0f / sqrtf(s2*(1.0f/128.0f) + 1e-5f);
#pragma unroll
    for (int j = 0; j < 8; ++j) {
      float y = (a[j]-mu)*rs*ln1g[sg*8+j] + ln1b[sg*8+j];
      h1c[pt*132 + sg*8 + j] = gelu_f(y);
    }
    __syncthreads();

    // GEMM2: 16 outputs q = sg*16 + j
    float c2[16];
#pragma unroll
    for (int j = 0; j < 16; ++j) c2[j] = p2b[sg*16 + j];
    const float* hr = h1c + pt*132;
    for (int e = 0; e < 128; ++e) {
      float hv = hr[e];
      float4 w0 = *(const float4*)(p2w + e*256 + sg*16);
      float4 w1 = *(const float4*)(p2w + e*256 + sg*16 + 4);
      float4 w2v = *(const float4*)(p2w + e*256 + sg*16 + 8);
      float4 w3 = *(const float4*)(p2w + e*256 + sg*16 + 12);
      c2[0]=fmaf(hv,w0.x,c2[0]);  c2[1]=fmaf(hv,w0.y,c2[1]);
      c2[2]=fmaf(hv,w0.z,c2[2]);  c2[3]=fmaf(hv,w0.w,c2[3]);
      c2[4]=fmaf(hv,w1.x,c2[4]);  c2[5]=fmaf(hv,w1.y,c2[5]);
      c2[6]=fmaf(hv,w1.z,c2[6]);  c2[7]=fmaf(hv,w1.w,c2[7]);
      c2[8]=fmaf(hv,w2v.x,c2[8]); c2[9]=fmaf(hv,w2v.y,c2[9]);
      c2[10]=fmaf(hv,w2v.z,c2[10]); c2[11]=fmaf(hv,w2v.w,c2[11]);
      c2[12]=fmaf(hv,w3.x,c2[12]); c2[13]=fmaf(hv,w3.y,c2[13]);
      c2[14]=fmaf(hv,w3.z,c2[14]); c2[15]=fmaf(hv,w3.w,c2[15]);
    }
    // LN over 256 (16 lanes x 16)
    float t1 = 0.f;
#pragma unroll
    for (int j = 0; j < 16; ++j) t1 += c2[j];
    t1 += __shfl_xor(t1,1); t1 += __shfl_xor(t1,2); t1 += __shfl_xor(t1,4); t1 += __shfl_xor(t1,8);
    float mu2 = t1 * (1.0f/256.0f);
    float t2 = 0.f;
#pragma unroll
    for (int j = 0; j < 16; ++j) { float dd = c2[j]-mu2; t2 += dd*dd; }
    t2 += __shfl_xor(t2,1); t2 += __shfl_xor(t2,2); t2 += __shfl_xor(t2,4); t2 += __shfl_xor(t2,8);
    float rs2 = 1.0f / sqrtf(t2*(1.0f/256.0f) + 1e-5f);
#pragma unroll
    for (int j = 0; j < 16; ++j) {
      float y = (c2[j]-mu2)*rs2*ln2g[sg*16+j] + ln2b[sg*16+j];
      float v = gelu_f(y);
      pmax[j] = fmaxf(pmax[j], v);
      psum[j] += v;
    }
  }

  __syncthreads();
#pragma unroll
  for (int j = 0; j < 16; ++j) {
    poolm[pt*256 + sg*16 + j] = pmax[j];
    pools[pt*256 + sg*16 + j] = psum[j];
  }
  __syncthreads();
  int q = tid & 255;
  if (tid < 256) {
    float mx = -INFINITY;
    for (int sl = 0; sl < 32; ++sl) mx = fmaxf(mx, poolm[sl*256 + q]);
    perbuf[(size_t)bt*576 + q] = mx;
  } else {
    float sm = 0.f;
    for (int sl = 0; sl < 32; ++sl) sm += pools[sl*256 + q];
    perbuf[(size_t)bt*576 + 256 + q] = sm * (1.0f/256.0f);
  }

  // fused frame MLP: 64 outputs for row bt
  if (tid < 64) {
    float x0 = xfr[bt*4], x1 = xfr[bt*4+1], x2 = xfr[bt*4+2], x3 = xfr[bt*4+3];
    float acc = f2b[tid];
#pragma unroll
    for (int e = 0; e < 32; ++e) {
      float hv = f1b[e];
      hv = fmaf(x0, f1w[e], hv);
      hv = fmaf(x1, f1w[32+e], hv);
      hv = fmaf(x2, f1w[64+e], hv);
      hv = fmaf(x3, f1w[96+e], hv);
      acc = fmaf(gelu_f(hv), f2w[e*64 + tid], acc);
    }
    perbuf[(size_t)bt*576 + 512 + tid] = acc;
  }
}

// ---------------- K6: 1x1 projection conv ----------------
__global__ __launch_bounds__(256) void proj_kernel(
    const float* __restrict__ per, const float* __restrict__ projw,
    const float* __restrict__ projb, float* __restrict__ hout) {
  __shared__ __align__(16) float sp[576];
  int bt = blockIdx.x, c = threadIdx.x;
  for (int i = c; i < 576; i += 256) sp[i] = per[(size_t)bt*576 + i];
  __syncthreads();
  float acc = projb[c];
  const float* wr = projw + (size_t)c*576;
  for (int i = 0; i < 144; ++i) {
    float4 wv = *(const float4*)(wr + i*4);
    float4 pv = *(const float4*)(sp + i*4);
    acc = fmaf(wv.x, pv.x, acc); acc = fmaf(wv.y, pv.y, acc);
    acc = fmaf(wv.z, pv.z, acc); acc = fmaf(wv.w, pv.w, acc);
  }
  hout[(size_t)bt*256 + c] = acc;
}

// ---------------- K7: conv3 + bn + gelu (+residual) ----------------
__global__ __launch_bounds__(256) void conv_bn_kernel(
    const float* __restrict__ hin, float* __restrict__ hout,
    const float* __restrict__ w, const float* __restrict__ bias,
    const float* __restrict__ g, const float* __restrict__ be,
    const float* __restrict__ m, const float* __restrict__ v,
    int residual) {
  __shared__ __align__(16) float win[768];   // [cin][dt]
  int bt = blockIdx.x, b = bt >> 5, t = bt & 31;
  int c = threadIdx.x;
  for (int i = c; i < 768; i += 256) {
    int cin = i / 3, dt = i - cin*3;
    int tt = t + dt - 1;
    win[i] = (tt >= 0 && tt < 32) ? hin[((size_t)b*32 + tt)*256 + cin] : 0.0f;
  }
  __syncthreads();
  float acc = bias[c];
  const float* wr = w + (size_t)c*768;
  for (int i = 0; i < 192; ++i) {
    float4 wv = *(const float4*)(wr + i*4);
    float4 pv = *(const float4*)(win + i*4);
    acc = fmaf(wv.x, pv.x, acc); acc = fmaf(wv.y, pv.y, acc);
    acc = fmaf(wv.z, pv.z, acc); acc = fmaf(wv.w, pv.w, acc);
  }
  float rsv = 1.0f / sqrtf(v[c] + 1e-5f);
  float y = (acc - m[c]) * rsv * g[c] + be[c];
  y = gelu_f(y);
  if (residual) y += win[c*3 + 1];
  hout[(size_t)bt*256 + c] = y;
}

// ---------------- K8: max-pool over T + head ----------------
__global__ __launch_bounds__(256) void poolhead_kernel(
    const float* __restrict__ hs, const float* __restrict__ h1w,
    const float* __restrict__ h1b, const float* __restrict__ h2w,
    const float* __restrict__ h2b, float* __restrict__ out) {
  __shared__ float pooled[256];
  __shared__ float hh[128];
  int b = blockIdx.x, tid = threadIdx.x;
  float mx = -INFINITY;
  for (int t = 0; t < 32; ++t)
    mx = fmaxf(mx, hs[((size_t)b*32 + t)*256 + tid]);
  pooled[tid] = mx;
  __syncthreads();
  if (tid < 128) {
    float acc = h1b[tid];
    for (int e = 0; e < 256; ++e) acc = fmaf(pooled[e], h1w[e*128 + tid], acc);
    hh[tid] = gelu_f(acc);
  }
  __syncthreads();
  if (tid < 25) {
    float acc = h2b[tid];
    for (int e = 0; e < 128; ++e) acc = fmaf(hh[e], h2w[e*25 + tid], acc);
    out[b*25 + tid] = acc;
  }
}

// ---------------- launch ----------------
extern "C" void kernel_launch(void* const* d_in, const int* in_sizes, int n_in,
                              void* d_out, int out_size, void* d_ws, size_t ws_size,
                              hipStream_t stream) {
  const float* x_pt = (const float*)d_in[0];
  const float* x_fr = (const float*)d_in[1];
  const float* ew1  = (const float*)d_in[2];
  const float* eg1  = (const float*)d_in[3];
  const float* eb1  = (const float*)d_in[4];
  const float* em1  = (const float*)d_in[5];
  const float* ev1  = (const float*)d_in[6];
  const float* ew2  = (const float*)d_in[7];
  const float* eg2  = (const float*)d_in[8];
  const float* eb2  = (const float*)d_in[9];
  const float* em2  = (const float*)d_in[10];
  const float* ev2  = (const float*)d_in[11];
  const float* p1w  = (const float*)d_in[12];
  const float* p1b  = (const float*)d_in[13];
  const float* ln1g = (const float*)d_in[14];
  const float* ln1b = (const float*)d_in[15];
  const float* p2w  = (const float*)d_in[16];
  const float* p2b  = (const float*)d_in[17];
  const float* ln2g = (const float*)d_in[18];
  const float* ln2b = (const float*)d_in[19];
  const float* f1w  = (const float*)d_in[20];
  const float* f1b  = (const float*)d_in[21];
  const float* f2w  = (const float*)d_in[22];
  const float* f2b  = (const float*)d_in[23];
  const float* projw= (const float*)d_in[24];
  const float* projb= (const float*)d_in[25];
  const float* cw[4] = {(const float*)d_in[26],(const float*)d_in[32],(const float*)d_in[38],(const float*)d_in[44]};
  const float* cb[4] = {(const float*)d_in[27],(const float*)d_in[33],(const float*)d_in[39],(const float*)d_in[45]};
  const float* cg[4] = {(const float*)d_in[28],(const float*)d_in[34],(const float*)d_in[40],(const float*)d_in[46]};
  const float* cbe[4]= {(const float*)d_in[29],(const float*)d_in[35],(const float*)d_in[41],(const float*)d_in[47]};
  const float* cm[4] = {(const float*)d_in[30],(const float*)d_in[36],(const float*)d_in[42],(const float*)d_in[48]};
  const float* cv[4] = {(const float*)d_in[31],(const float*)d_in[37],(const float*)d_in[43],(const float*)d_in[49]};
  const float* h1w  = (const float*)d_in[50];
  const float* h1b  = (const float*)d_in[51];
  const float* h2w  = (const float*)d_in[52];
  const float* h2b  = (const float*)d_in[53];
  float* out = (float*)d_out;

  char* ws = (char*)d_ws;
  int*   idxw   = (int*)ws;                                   // 4 MB
  float* perbuf = (float*)ws;                                 // reused after edgeconv
  float* hs0    = (float*)(ws + 0x90000);
  float* hs1    = (float*)(ws + 0x90000 + 0x40000);
  float* hs2    = (float*)(ws + 0x90000 + 2*0x40000);
  float* hs3    = (float*)(ws + 0x90000 + 3*0x40000);
  float* hs4    = (float*)(ws + 0x90000 + 4*0x40000);
  float* Af     = (float*)(ws + ((size_t)4  << 20));
  float* Bfw    = (float*)(ws + ((size_t)20 << 20));
  float* localf = (float*)(ws + ((size_t)36 << 20));

  knn_kernel<<<NBT*64, 256, 0, stream>>>(x_pt, idxw);
  featAB_kernel<<<(NBT*NP*64)/256, 256, 0, stream>>>(x_pt, ew1, Af, Bfw);
  edgeconv_kernel<<<(NBT*NP)/NPB, 256, 0, stream>>>(Af, Bfw, idxw, ew2,
      eg1, eb1, em1, ev1, eg2, eb2, em2, ev2, localf);
  p1p2_kernel<<<NBT, 512, 0, stream>>>(localf, x_pt, p1w, p1b, ln1g, ln1b,
      p2w, p2b, ln2g, ln2b, x_fr, f1w, f1b, f2w, f2b, perbuf);
  proj_kernel<<<NBT, 256, 0, stream>>>(perbuf, projw, projb, hs0);
  conv_bn_kernel<<<NBT, 256, 0, stream>>>(hs0, hs1, cw[0], cb[0], cg[0], cbe[0], cm[0], cv[0], 0);
  conv_bn_kernel<<<NBT, 256, 0, stream>>>(hs1, hs2, cw[1], cb[1], cg[1], cbe[1], cm[1], cv[1], 1);
  conv_bn_kernel<<<NBT, 256, 0, stream>>>(hs2, hs3, cw[2], cb[2], cg[2], cbe[2], cm[2], cv[2], 1);
  conv_bn_kernel<<<NBT, 256, 0, stream>>>(hs3, hs4, cw[3], cb[3], cg[3], cbe[3], cm[3], cv[3], 1);
  poolhead_kernel<<<8, 256, 0, stream>>>(hs4, h1w, h1b, h2w, h2b, out);
}